// Round 8
// baseline (288.796 us; speedup 1.0000x reference)
//
#include <hip/hip_runtime.h>
#include <hip/hip_bf16.h>

// Problem constants: B=2, Lq=4096, C=384, M=4, H=6, P=4, Lv=1, 64x64, Dh=64.
#define RTOT 8192      // B*Lq
#define C_   384
#define M_   4
#define KOUT 1536      // M_*C_

typedef __bf16 bf16;
typedef bf16  bf16x8 __attribute__((ext_vector_type(8)));
typedef float f32x4  __attribute__((ext_vector_type(4)));

// async global->LDS, 16B per lane, linear LDS dest (wave-uniform base + lane*16)
#define GLOAD_LDS16(g, l) __builtin_amdgcn_global_load_lds( \
    (const __attribute__((address_space(1))) unsigned int*)(g), \
    (__attribute__((address_space(3))) unsigned int*)(l), 16, 0, 0)

// counted vmcnt wait + workgroup barrier (T3/T4: never drain to 0 mid-loop).
#define WAITB(N) do { \
    asm volatile("s_waitcnt vmcnt(" #N ")\n\ts_barrier" ::: "memory"); \
    __builtin_amdgcn_sched_barrier(0); } while (0)

// ---------------------------------------------------------------------------
// prep: fused weight-prep (cvt) + LayerNorm + split-K counter reset.
//   blocks [0, 10240): LN, which = bid/2048 (0=query, 1..4=feats), 4 rows/blk
//   blocks [10240, 11264): grid-stride cvt over S4 elems + 192 counter zeros
// ---------------------------------------------------------------------------
#define S0 589824    // WvT:    4*384*384
#define S1 786432    // +WoffawT: 4*128*384
#define S2 1376256   // +WoutT: 384*1536
#define S3 1376768   // +oabias: 4*128
#define S4 1377152   // +boutbig: 384
#define S5 1377344   // +counters: 192

__global__ __launch_bounds__(256) void prep_kernel(
    const float* __restrict__ query, const float* __restrict__ feat,
    const float* __restrict__ feat_other,
    const float* __restrict__ qn_g, const float* __restrict__ qn_b,
    const float* __restrict__ fn_g, const float* __restrict__ fn_b,
    bf16* __restrict__ qn, bf16* __restrict__ fn,
    const float* __restrict__ Wv, const float* __restrict__ Woff,
    const float* __restrict__ Waw, const float* __restrict__ Wout,
    const float* __restrict__ gamma, const float* __restrict__ boff,
    const float* __restrict__ baw, const float* __restrict__ bout,
    bf16* __restrict__ WvT, bf16* __restrict__ WoffawT, bf16* __restrict__ WoutT,
    float* __restrict__ oabias, float* __restrict__ boutbig, int* __restrict__ counters)
{
    const int bid = blockIdx.x;
    const int tid = threadIdx.x;
    if (bid < 10240) {
        // ---- LayerNorm: 4 waves, one row each; float2 loads, bf16x2 stores
        const int which = bid / 2048;
        const int xb    = bid % 2048;
        const int r = xb * 4 + (tid >> 6);
        const int lane = tid & 63;
        const float* src; const float* g; const float* bb; bf16* dst;
        if (which == 0) { src = query; g = qn_g; bb = qn_b; dst = qn; }
        else {
            int m = which - 1;
            src = (m == 0) ? feat : feat_other + (size_t)(m - 1) * RTOT * C_;
            g = fn_g + m * C_; bb = fn_b + m * C_; dst = fn + (size_t)m * RTOT * C_;
        }
        src += (size_t)r * C_; dst += (size_t)r * C_;
        float2 v[3]; float s = 0.f, sq = 0.f;
#pragma unroll
        for (int j = 0; j < 3; ++j) {
            v[j] = *reinterpret_cast<const float2*>(src + (lane + j * 64) * 2);
            s += v[j].x + v[j].y; sq += v[j].x * v[j].x + v[j].y * v[j].y;
        }
#pragma unroll
        for (int o = 1; o < 64; o <<= 1) {
            s += __shfl_xor(s, o);
            sq += __shfl_xor(sq, o);
        }
        const float mean = s * (1.f / C_);
        const float var  = sq * (1.f / C_) - mean * mean;
        const float rs   = rsqrtf(var + 1e-6f);
#pragma unroll
        for (int j = 0; j < 3; ++j) {
            const int c = (lane + j * 64) * 2;
            union { bf16 h2[2]; unsigned int u; } o;
            o.h2[0] = (bf16)((v[j].x - mean) * rs * g[c] + bb[c]);
            o.h2[1] = (bf16)((v[j].y - mean) * rs * g[c + 1] + bb[c + 1]);
            *reinterpret_cast<unsigned int*>(dst + c) = o.u;
        }
        return;
    }
    // ---- cvt (weight prep) + counter reset, grid-stride
    for (int idx = (bid - 10240) * 256 + tid; idx < S5; idx += 1024 * 256) {
        if (idx < S0) {
            int t = idx; int m = t / (C_ * C_); int rr = t % (C_ * C_);
            int n = rr / C_, k = rr % C_;
            WvT[t] = (bf16)Wv[(size_t)m * C_ * C_ + (size_t)k * C_ + n];
        } else if (idx < S1) {
            int t = idx - S0; int m = t / (128 * C_); int rr = t % (128 * C_);
            int n = rr / C_, k = rr % C_;
            float v = 0.f;
            if (n < 48)      v = Woff[(size_t)m * C_ * 48 + (size_t)k * 48 + n];
            else if (n < 72) v = Waw[(size_t)m * C_ * 24 + (size_t)k * 24 + (n - 48)];
            WoffawT[t] = (bf16)v;
        } else if (idx < S2) {
            int t = idx - S1; int n = t / KOUT; int kk = t % KOUT;
            int m = kk / C_, k = kk % C_;
            WoutT[t] = (bf16)(Wout[(size_t)m * C_ * C_ + (size_t)k * C_ + n] * gamma[m * C_ + n]);
        } else if (idx < S3) {
            int t = idx - S2; int m = t / 128; int n = t % 128;
            float v = 0.f;
            if (n < 48)      v = boff[m * 48 + n];
            else if (n < 72) v = baw[m * 24 + (n - 48)];
            oabias[t] = v;
        } else if (idx < S4) {
            int c = idx - S3;
            float s = 0.f;
            for (int m = 0; m < M_; ++m) s += gamma[m * C_ + c] * bout[m * C_ + c];
            boutbig[c] = s;
        } else {
            counters[idx - S4] = 0;
        }
    }
}

// ---------------------------------------------------------------------------
// Shared GEMM pipeline: 128x128 tile, BK=32, NK=12 K-steps (K-window 384),
// 4 waves (2x2), 4x4 16x16 frags/wave. 3 LDS buffer pairs, 2-ahead counted
// vmcnt pipeline. Both-sides swizzle: 16B slot s of each 64B LDS row holds
// global col-chunk s ^ ((row>>1)&3); ds_read applies the same XOR.
// mode: 0 = bf16 out + bias, 1 = f32 out + bias, 3 = bf16 raw (split-K part).
// ---------------------------------------------------------------------------
__device__ __forceinline__ void gemm_pipe(
    const bf16* __restrict__ A, int lda,
    const bf16* __restrict__ W, int ldw,
    const float* __restrict__ bias,
    void* __restrict__ outP, int ldo, int mode,
    int brow, int bcol, bf16* As, bf16* Bs)
{
    const int tid = threadIdx.x;
    const int lane = tid & 63, wave = tid >> 6;
    const int wr = wave >> 1, wc = wave & 1;
    const int lr = lane & 15, lg = lane >> 4;

    const int r0 = tid >> 2, s0 = tid & 3;
    const int r1 = r0 + 64;
    const long long aoff0 = (long long)(brow + r0) * lda + (s0 ^ ((r0 >> 1) & 3)) * 8;
    const long long aoff1 = (long long)(brow + r1) * lda + (s0 ^ ((r1 >> 1) & 3)) * 8;
    const long long woff0 = (long long)(bcol + r0) * ldw + (s0 ^ ((r0 >> 1) & 3)) * 8;
    const long long woff1 = (long long)(bcol + r1) * ldw + (s0 ^ ((r1 >> 1) & 3)) * 8;

    int aRd[4], bRd[4];
#pragma unroll
    for (int i = 0; i < 4; ++i) {
        const int ra = wr * 64 + i * 16 + lr;
        const int rb = wc * 64 + i * 16 + lr;
        aRd[i] = ra * 32 + (lg ^ ((ra >> 1) & 3)) * 8;
        bRd[i] = rb * 32 + (lg ^ ((rb >> 1) & 3)) * 8;
    }

    f32x4 acc[4][4] = {};

#pragma unroll
    for (int t = 0; t < 2; ++t) {
        GLOAD_LDS16(A + aoff0 + t * 32, (char*)As + t * 8192 + tid * 16);
        GLOAD_LDS16(A + aoff1 + t * 32, (char*)As + t * 8192 + (tid + 256) * 16);
        GLOAD_LDS16(W + woff0 + t * 32, (char*)Bs + t * 8192 + tid * 16);
        GLOAD_LDS16(W + woff1 + t * 32, (char*)Bs + t * 8192 + (tid + 256) * 16);
    }

#pragma unroll
    for (int kt = 0; kt < 12; ++kt) {
        if (kt + 1 < 12) { WAITB(4); } else { WAITB(0); }
        const int cb = kt % 3, ib = (kt + 2) % 3;
        if (kt + 2 < 12) {
            GLOAD_LDS16(A + aoff0 + (kt + 2) * 32, (char*)As + ib * 8192 + tid * 16);
            GLOAD_LDS16(A + aoff1 + (kt + 2) * 32, (char*)As + ib * 8192 + (tid + 256) * 16);
            GLOAD_LDS16(W + woff0 + (kt + 2) * 32, (char*)Bs + ib * 8192 + tid * 16);
            GLOAD_LDS16(W + woff1 + (kt + 2) * 32, (char*)Bs + ib * 8192 + (tid + 256) * 16);
        }
        bf16x8 af[4], bfr[4];
#pragma unroll
        for (int mi = 0; mi < 4; ++mi)
            af[mi] = *reinterpret_cast<const bf16x8*>(&As[cb * 4096 + aRd[mi]]);
#pragma unroll
        for (int ni = 0; ni < 4; ++ni)
            bfr[ni] = *reinterpret_cast<const bf16x8*>(&Bs[cb * 4096 + bRd[ni]]);
#pragma unroll
        for (int mi = 0; mi < 4; ++mi)
#pragma unroll
            for (int ni = 0; ni < 4; ++ni)
                acc[mi][ni] = __builtin_amdgcn_mfma_f32_16x16x32_bf16(
                    af[mi], bfr[ni], acc[mi][ni], 0, 0, 0);
    }

#pragma unroll
    for (int mi = 0; mi < 4; ++mi) {
#pragma unroll
        for (int ni = 0; ni < 4; ++ni) {
#pragma unroll
            for (int rr = 0; rr < 4; ++rr) {
                const int row = brow + wr * 64 + mi * 16 + lg * 4 + rr;
                const int col = bcol + wc * 64 + ni * 16 + lr;
                float v = acc[mi][ni][rr];
                if (mode != 3) v += bias[col];
                const long long o = (long long)row * ldo + col;
                if (mode == 1) ((float*)outP)[o] = v;
                else           ((bf16*)outP)[o] = (bf16)v;
            }
        }
    }
}

// Fused value-GEMM (768 blocks) + offaw-GEMM (256 blocks) in one dispatch.
__global__ __launch_bounds__(256) void g01_kernel(
    const bf16* __restrict__ fn, const bf16* __restrict__ qn,
    const bf16* __restrict__ WvT, const bf16* __restrict__ WoffawT,
    const float* __restrict__ bv, const float* __restrict__ oabias,
    bf16* __restrict__ value, float* __restrict__ offaw)
{
    __shared__ __align__(16) bf16 As[3 * 4096];
    __shared__ __align__(16) bf16 Bs[3 * 4096];
    const int id = blockIdx.x;
    if (id < 768) {                       // value[m] = fn[m] @ WvT[m] + bv[m]
        const int rowb = id & 63, q = id >> 6;   // q 0..11
        const int colb = q % 3, m = q / 3;
        gemm_pipe(fn + (long long)m * RTOT * C_, C_,
                  WvT + (long long)m * C_ * C_, C_,
                  bv + m * C_, value + (long long)m * RTOT * C_, C_, 0,
                  rowb * 128, colb * 128, As, Bs);
    } else {                              // offaw[m] = qn @ WoffawT[m] + oabias
        const int id2 = id - 768;
        const int rowb = id2 & 63, m = id2 >> 6;
        gemm_pipe(qn, C_, WoffawT + (long long)m * 128 * C_, C_,
                  oabias + m * 128, offaw + (long long)m * RTOT * 128, 128, 1,
                  rowb * 128, 0, As, Bs);
    }
}

// out-GEMM split-K=4 (chunk = modality) with fused last-block join:
//   partial[kc] = attn[:,kc*384:] @ Wout_kc  (bf16)
//   last block per (rowb,colb) tile sums 4 partials in fixed order + query
//   + boutbig -> out (deterministic).
__global__ __launch_bounds__(256) void g2_kernel(
    const bf16* __restrict__ attn, const bf16* __restrict__ WoutT,
    bf16* __restrict__ partial, const float* __restrict__ query,
    const float* __restrict__ boutbig, float* __restrict__ out,
    int* __restrict__ counters)
{
    __shared__ __align__(16) bf16 As[3 * 4096];
    __shared__ __align__(16) bf16 Bs[3 * 4096];
    const int tile = blockIdx.x >> 2;     // 0..191
    const int kc   = blockIdx.x & 3;
    const int rowb = tile % 64, colb = tile / 64;   // colb 0..2
    gemm_pipe(attn + kc * C_, KOUT, WoutT + kc * C_, KOUT, nullptr,
              partial + (long long)kc * RTOT * C_, C_, 3,
              rowb * 128, colb * 128, As, Bs);

    __threadfence();
    __shared__ int lastv;
    if (threadIdx.x == 0) lastv = atomicAdd(&counters[tile], 1);
    __syncthreads();
    if (lastv != 3) return;
    __threadfence();

    const int row  = rowb * 128 + (threadIdx.x >> 1);
    const int cb0  = colb * 128 + (threadIdx.x & 1) * 64;
    const long long rb = (long long)row * C_;
#pragma unroll
    for (int j = 0; j < 8; ++j) {
        const int col = cb0 + j * 8;
        float s[8];
#pragma unroll
        for (int jj = 0; jj < 8; ++jj) s[jj] = query[rb + col + jj] + boutbig[col + jj];
#pragma unroll
        for (int z = 0; z < 4; ++z) {
            bf16x8 p = *reinterpret_cast<const bf16x8*>(partial + (long long)z * RTOT * C_ + rb + col);
#pragma unroll
            for (int jj = 0; jj < 8; ++jj) s[jj] += (float)p[jj];
        }
#pragma unroll
        for (int jj = 0; jj < 8; ++jj) out[rb + col + jj] = s[jj];
    }
}

// ---------------------------------------------------------------------------
// Deformable sampling. Block = 4 rows of one (m,b); 384 threads.
// Phase 1 (96 threads): per (row,h,p) softmax + bilinear -> 4 {weight,
//   byte-offset} pairs in LDS (validity folded, offsets premultiplied).
// Phase 2 (4 rows x 6 heads x 16 lanes): lane owns 4 channels, 16 u64 gathers
//   issued back-to-back (MLP), then 64 FMAs. Half the waves of the u32 form.
// Grid: bid&7 = m*2+b -> each XCD keeps one 3.1MB value slice L2-resident.
// ---------------------------------------------------------------------------
struct WP { float w; int off; };

__global__ __launch_bounds__(384) void sample_kernel(
    const float* __restrict__ offaw, const float* __restrict__ ref,
    const bf16* __restrict__ value, bf16* __restrict__ attn)
{
    const int bid   = blockIdx.x;
    const int combo = bid & 7;
    const int quad  = bid >> 3;          // 0..1023
    const int m = combo >> 1, b = combo & 1;
    const int r0 = b * 4096 + quad * 4;

    __shared__ WP wp_s[4][24][4];

    const int t = threadIdx.x;
    if (t < 96) {
        const int row = t / 24;
        const int i   = t % 24;          // h*4+p  (aligned-4 groups: same row,h)
        const int h = i >> 2, p = i & 3;
        const int r = r0 + row;
        const float* oa = offaw + ((long long)m * RTOT + r) * 128;
        float e = oa[48 + h * 4 + p];
        float mx = fmaxf(e, __shfl_xor(e, 1));
        mx = fmaxf(mx, __shfl_xor(mx, 2));
        float ex = expf(e - mx);
        float s = ex;
        s += __shfl_xor(s, 1);
        s += __shfl_xor(s, 2);
        const float aw = ex / s;
        const float x = ref[r * 2 + 0] * 64.f - 0.5f + oa[h * 8 + p * 2 + 0];
        const float y = ref[r * 2 + 1] * 64.f - 0.5f + oa[h * 8 + p * 2 + 1];
        const float xf = floorf(x), yf = floorf(y);
        const float wx = x - xf, wy = y - yf;
        const int x0 = (int)xf, y0 = (int)yf;
        const bool xok0 = (x0 >= 0) && (x0 < 64);
        const bool xok1 = (x0 >= -1) && (x0 < 63);
        const bool yok0 = (y0 >= 0) && (y0 < 64);
        const bool yok1 = (y0 >= -1) && (y0 < 63);
        const int xc0 = min(max(x0, 0), 63),     xc1 = min(max(x0 + 1, 0), 63);
        const int yc0 = min(max(y0, 0), 63),     yc1 = min(max(y0 + 1, 0), 63);
        WP w0 = { aw * (1.f - wx) * (1.f - wy) * (float)(xok0 && yok0), (yc0 * 64 + xc0) * (C_ * 2) };
        WP w1 = { aw * wx         * (1.f - wy) * (float)(xok1 && yok0), (yc0 * 64 + xc1) * (C_ * 2) };
        WP w2 = { aw * (1.f - wx) * wy         * (float)(xok0 && yok1), (yc1 * 64 + xc0) * (C_ * 2) };
        WP w3 = { aw * wx         * wy         * (float)(xok1 && yok1), (yc1 * 64 + xc1) * (C_ * 2) };
        wp_s[row][i][0] = w0;  wp_s[row][i][1] = w1;
        wp_s[row][i][2] = w2;  wp_s[row][i][3] = w3;
    }
    __syncthreads();

    const int row = t / 96;              // 0..3
    const int tl  = t % 96;
    const int h   = tl >> 4;             // 0..5
    const int l16 = tl & 15;             // 4 channels each
    const int r   = r0 + row;
    const char* vb = (const char*)(value
        + ((long long)m * RTOT + (long long)b * 4096) * C_ + h * 64 + l16 * 4);

    float wreg[16]; int oreg[16]; unsigned long long vreg[16];
#pragma unroll
    for (int i = 0; i < 16; ++i) {
        WP wp = wp_s[row][h * 4 + (i >> 2)][i & 3];
        wreg[i] = wp.w; oreg[i] = wp.off;
    }
#pragma unroll
    for (int i = 0; i < 16; ++i)
        vreg[i] = *reinterpret_cast<const unsigned long long*>(vb + oreg[i]);
    float a0 = 0.f, a1 = 0.f, a2 = 0.f, a3 = 0.f;
#pragma unroll
    for (int i = 0; i < 16; ++i) {
        const unsigned int lo = (unsigned int)vreg[i];
        const unsigned int hi = (unsigned int)(vreg[i] >> 32);
        a0 += wreg[i] * __builtin_bit_cast(float, lo << 16);
        a1 += wreg[i] * __builtin_bit_cast(float, lo & 0xffff0000u);
        a2 += wreg[i] * __builtin_bit_cast(float, hi << 16);
        a3 += wreg[i] * __builtin_bit_cast(float, hi & 0xffff0000u);
    }
    union { bf16 h4[4]; unsigned long long u; } o;
    o.h4[0] = (bf16)a0; o.h4[1] = (bf16)a1; o.h4[2] = (bf16)a2; o.h4[3] = (bf16)a3;
    *reinterpret_cast<unsigned long long*>(attn + (long long)r * KOUT + m * C_ + h * 64 + l16 * 4) = o.u;
}

// ---------------------------------------------------------------------------
extern "C" void kernel_launch(void* const* d_in, const int* in_sizes, int n_in,
                              void* d_out, int out_size, void* d_ws, size_t ws_size,
                              hipStream_t stream)
{
    const float* query      = (const float*)d_in[0];
    const float* ref        = (const float*)d_in[1];
    const float* feat       = (const float*)d_in[2];
    const float* feat_other = (const float*)d_in[3];
    const float* qn_g = (const float*)d_in[4];
    const float* qn_b = (const float*)d_in[5];
    const float* fn_g = (const float*)d_in[6];
    const float* fn_b = (const float*)d_in[7];
    const float* Wv   = (const float*)d_in[8];
    const float* bv   = (const float*)d_in[9];
    const float* Woff = (const float*)d_in[10];
    const float* boff = (const float*)d_in[11];
    const float* Waw  = (const float*)d_in[12];
    const float* baw  = (const float*)d_in[13];
    const float* Wout = (const float*)d_in[14];
    const float* bout = (const float*)d_in[15];
    const float* gamma = (const float*)d_in[16];
    float* out = (float*)d_out;

    char* ws = (char*)d_ws;
    size_t off = 0;
    auto carve = [&](size_t bytes) { char* p = ws + off; off += (bytes + 255) & ~(size_t)255; return p; };
    bf16*  qn      = (bf16*)carve((size_t)RTOT * C_ * 2);
    bf16*  fn      = (bf16*)carve((size_t)M_ * RTOT * C_ * 2);
    bf16*  value   = (bf16*)carve((size_t)M_ * RTOT * C_ * 2);
    bf16*  attn    = (bf16*)carve((size_t)RTOT * KOUT * 2);
    bf16*  partial = (bf16*)carve((size_t)M_ * RTOT * C_ * 2);
    float* offaw   = (float*)carve((size_t)M_ * RTOT * 128 * 4);
    bf16*  WvT     = (bf16*)carve((size_t)M_ * C_ * C_ * 2);
    bf16*  WoffawT = (bf16*)carve((size_t)M_ * 128 * C_ * 2);
    bf16*  WoutT   = (bf16*)carve((size_t)C_ * KOUT * 2);
    float* oabias  = (float*)carve((size_t)M_ * 128 * 4);
    float* boutbig = (float*)carve((size_t)C_ * 4);
    int*   counters = (int*)carve(192 * 4);

    // prep: LN (10240 blocks) + weight cvt (1024 blocks) + counter reset
    prep_kernel<<<11264, 256, 0, stream>>>(query, feat, feat_other,
                                           qn_g, qn_b, fn_g, fn_b, qn, fn,
                                           Wv, Woff, Waw, Wout, gamma, boff, baw, bout,
                                           WvT, WoffawT, WoutT, oabias, boutbig, counters);
    // value[m] (768 blocks) + offaw[m] (256 blocks), one dispatch
    g01_kernel<<<1024, 256, 0, stream>>>(fn, qn, WvT, WoffawT, bv, oabias, value, offaw);
    // sampling -> attn [R][1536] bf16
    sample_kernel<<<dim3(RTOT * M_ / 4), 384, 0, stream>>>(offaw, ref, value, attn);
    // split-K out-GEMM + fused deterministic join
    g2_kernel<<<768, 256, 0, stream>>>(attn, WoutT, partial, query, boutbig, out, counters);
}

// Round 9
// 107.292 us; speedup vs baseline: 2.6917x; 2.6917x over previous
//
#include <hip/hip_runtime.h>
#include <hip/hip_bf16.h>

// Problem constants: B=2, Lq=4096, C=384, M=4, H=6, P=4, Lv=1, 64x64, Dh=64.
#define RTOT 8192      // B*Lq
#define C_   384
#define M_   4
#define KOUT 1536      // M_*C_

typedef __bf16 bf16;
typedef bf16  bf16x8 __attribute__((ext_vector_type(8)));
typedef float f32x4  __attribute__((ext_vector_type(4)));

// async global->LDS, 16B per lane, linear LDS dest (wave-uniform base + lane*16)
#define GLOAD_LDS16(g, l) __builtin_amdgcn_global_load_lds( \
    (const __attribute__((address_space(1))) unsigned int*)(g), \
    (__attribute__((address_space(3))) unsigned int*)(l), 16, 0, 0)

// counted vmcnt wait + workgroup barrier (T3/T4: never drain to 0 mid-loop).
#define WAITB(N) do { \
    asm volatile("s_waitcnt vmcnt(" #N ")\n\ts_barrier" ::: "memory"); \
    __builtin_amdgcn_sched_barrier(0); } while (0)

// ---------------------------------------------------------------------------
// prep: fused weight-prep (cvt) + LayerNorm.
//   blocks [0, 10240): LN, which = bid/2048 (0=query, 1..4=feats), 4 rows/blk
//   blocks [10240, 11264): grid-stride cvt over S4 elems
// ---------------------------------------------------------------------------
#define S0 589824    // WvT:    4*384*384
#define S1 786432    // +WoffawT: 4*128*384
#define S2 1376256   // +WoutT: 384*1536
#define S3 1376768   // +oabias: 4*128
#define S4 1377152   // +boutbig: 384

__global__ __launch_bounds__(256) void prep_kernel(
    const float* __restrict__ query, const float* __restrict__ feat,
    const float* __restrict__ feat_other,
    const float* __restrict__ qn_g, const float* __restrict__ qn_b,
    const float* __restrict__ fn_g, const float* __restrict__ fn_b,
    bf16* __restrict__ qn, bf16* __restrict__ fn,
    const float* __restrict__ Wv, const float* __restrict__ Woff,
    const float* __restrict__ Waw, const float* __restrict__ Wout,
    const float* __restrict__ gamma, const float* __restrict__ boff,
    const float* __restrict__ baw, const float* __restrict__ bout,
    bf16* __restrict__ WvT, bf16* __restrict__ WoffawT, bf16* __restrict__ WoutT,
    float* __restrict__ oabias, float* __restrict__ boutbig)
{
    const int bid = blockIdx.x;
    const int tid = threadIdx.x;
    if (bid < 10240) {
        // ---- LayerNorm: 4 waves, one row each; float2 loads, bf16x2 stores
        const int which = bid / 2048;
        const int xb    = bid % 2048;
        const int r = xb * 4 + (tid >> 6);
        const int lane = tid & 63;
        const float* src; const float* g; const float* bb; bf16* dst;
        if (which == 0) { src = query; g = qn_g; bb = qn_b; dst = qn; }
        else {
            int m = which - 1;
            src = (m == 0) ? feat : feat_other + (size_t)(m - 1) * RTOT * C_;
            g = fn_g + m * C_; bb = fn_b + m * C_; dst = fn + (size_t)m * RTOT * C_;
        }
        src += (size_t)r * C_; dst += (size_t)r * C_;
        float2 v[3]; float s = 0.f, sq = 0.f;
#pragma unroll
        for (int j = 0; j < 3; ++j) {
            v[j] = *reinterpret_cast<const float2*>(src + (lane + j * 64) * 2);
            s += v[j].x + v[j].y; sq += v[j].x * v[j].x + v[j].y * v[j].y;
        }
#pragma unroll
        for (int o = 1; o < 64; o <<= 1) {
            s += __shfl_xor(s, o);
            sq += __shfl_xor(sq, o);
        }
        const float mean = s * (1.f / C_);
        const float var  = sq * (1.f / C_) - mean * mean;
        const float rs   = rsqrtf(var + 1e-6f);
#pragma unroll
        for (int j = 0; j < 3; ++j) {
            const int c = (lane + j * 64) * 2;
            union { bf16 h2[2]; unsigned int u; } o;
            o.h2[0] = (bf16)((v[j].x - mean) * rs * g[c] + bb[c]);
            o.h2[1] = (bf16)((v[j].y - mean) * rs * g[c + 1] + bb[c + 1]);
            *reinterpret_cast<unsigned int*>(dst + c) = o.u;
        }
        return;
    }
    // ---- cvt (weight prep), grid-stride
    for (int idx = (bid - 10240) * 256 + tid; idx < S4; idx += 1024 * 256) {
        if (idx < S0) {
            int t = idx; int m = t / (C_ * C_); int rr = t % (C_ * C_);
            int n = rr / C_, k = rr % C_;
            WvT[t] = (bf16)Wv[(size_t)m * C_ * C_ + (size_t)k * C_ + n];
        } else if (idx < S1) {
            int t = idx - S0; int m = t / (128 * C_); int rr = t % (128 * C_);
            int n = rr / C_, k = rr % C_;
            float v = 0.f;
            if (n < 48)      v = Woff[(size_t)m * C_ * 48 + (size_t)k * 48 + n];
            else if (n < 72) v = Waw[(size_t)m * C_ * 24 + (size_t)k * 24 + (n - 48)];
            WoffawT[t] = (bf16)v;
        } else if (idx < S2) {
            int t = idx - S1; int n = t / KOUT; int kk = t % KOUT;
            int m = kk / C_, k = kk % C_;
            WoutT[t] = (bf16)(Wout[(size_t)m * C_ * C_ + (size_t)k * C_ + n] * gamma[m * C_ + n]);
        } else if (idx < S3) {
            int t = idx - S2; int m = t / 128; int n = t % 128;
            float v = 0.f;
            if (n < 48)      v = boff[m * 48 + n];
            else if (n < 72) v = baw[m * 24 + (n - 48)];
            oabias[t] = v;
        } else {
            int c = idx - S3;
            float s = 0.f;
            for (int m = 0; m < M_; ++m) s += gamma[m * C_ + c] * bout[m * C_ + c];
            boutbig[c] = s;
        }
    }
}

// ---------------------------------------------------------------------------
// Shared GEMM pipeline: 128x128 tile, BK=32, NK=12 K-steps (K-window 384),
// 4 waves (2x2), 4x4 16x16 frags/wave. 3 LDS buffer pairs, 2-ahead counted
// vmcnt pipeline. Both-sides swizzle: 16B slot s of each 64B LDS row holds
// global col-chunk s ^ ((row>>1)&3); ds_read applies the same XOR.
// mode: 0 = bf16 out + bias, 1 = f32 out + bias, 3 = bf16 raw (split-K part).
// ---------------------------------------------------------------------------
__device__ __forceinline__ void gemm_pipe(
    const bf16* __restrict__ A, int lda,
    const bf16* __restrict__ W, int ldw,
    const float* __restrict__ bias,
    void* __restrict__ outP, int ldo, int mode,
    int brow, int bcol, bf16* As, bf16* Bs)
{
    const int tid = threadIdx.x;
    const int lane = tid & 63, wave = tid >> 6;
    const int wr = wave >> 1, wc = wave & 1;
    const int lr = lane & 15, lg = lane >> 4;

    const int r0 = tid >> 2, s0 = tid & 3;
    const int r1 = r0 + 64;
    const long long aoff0 = (long long)(brow + r0) * lda + (s0 ^ ((r0 >> 1) & 3)) * 8;
    const long long aoff1 = (long long)(brow + r1) * lda + (s0 ^ ((r1 >> 1) & 3)) * 8;
    const long long woff0 = (long long)(bcol + r0) * ldw + (s0 ^ ((r0 >> 1) & 3)) * 8;
    const long long woff1 = (long long)(bcol + r1) * ldw + (s0 ^ ((r1 >> 1) & 3)) * 8;

    int aRd[4], bRd[4];
#pragma unroll
    for (int i = 0; i < 4; ++i) {
        const int ra = wr * 64 + i * 16 + lr;
        const int rb = wc * 64 + i * 16 + lr;
        aRd[i] = ra * 32 + (lg ^ ((ra >> 1) & 3)) * 8;
        bRd[i] = rb * 32 + (lg ^ ((rb >> 1) & 3)) * 8;
    }

    f32x4 acc[4][4] = {};

#pragma unroll
    for (int t = 0; t < 2; ++t) {
        GLOAD_LDS16(A + aoff0 + t * 32, (char*)As + t * 8192 + tid * 16);
        GLOAD_LDS16(A + aoff1 + t * 32, (char*)As + t * 8192 + (tid + 256) * 16);
        GLOAD_LDS16(W + woff0 + t * 32, (char*)Bs + t * 8192 + tid * 16);
        GLOAD_LDS16(W + woff1 + t * 32, (char*)Bs + t * 8192 + (tid + 256) * 16);
    }

#pragma unroll
    for (int kt = 0; kt < 12; ++kt) {
        if (kt + 1 < 12) { WAITB(4); } else { WAITB(0); }
        const int cb = kt % 3, ib = (kt + 2) % 3;
        if (kt + 2 < 12) {
            GLOAD_LDS16(A + aoff0 + (kt + 2) * 32, (char*)As + ib * 8192 + tid * 16);
            GLOAD_LDS16(A + aoff1 + (kt + 2) * 32, (char*)As + ib * 8192 + (tid + 256) * 16);
            GLOAD_LDS16(W + woff0 + (kt + 2) * 32, (char*)Bs + ib * 8192 + tid * 16);
            GLOAD_LDS16(W + woff1 + (kt + 2) * 32, (char*)Bs + ib * 8192 + (tid + 256) * 16);
        }
        bf16x8 af[4], bfr[4];
#pragma unroll
        for (int mi = 0; mi < 4; ++mi)
            af[mi] = *reinterpret_cast<const bf16x8*>(&As[cb * 4096 + aRd[mi]]);
#pragma unroll
        for (int ni = 0; ni < 4; ++ni)
            bfr[ni] = *reinterpret_cast<const bf16x8*>(&Bs[cb * 4096 + bRd[ni]]);
#pragma unroll
        for (int mi = 0; mi < 4; ++mi)
#pragma unroll
            for (int ni = 0; ni < 4; ++ni)
                acc[mi][ni] = __builtin_amdgcn_mfma_f32_16x16x32_bf16(
                    af[mi], bfr[ni], acc[mi][ni], 0, 0, 0);
    }

#pragma unroll
    for (int mi = 0; mi < 4; ++mi) {
#pragma unroll
        for (int ni = 0; ni < 4; ++ni) {
#pragma unroll
            for (int rr = 0; rr < 4; ++rr) {
                const int row = brow + wr * 64 + mi * 16 + lg * 4 + rr;
                const int col = bcol + wc * 64 + ni * 16 + lr;
                float v = acc[mi][ni][rr];
                if (mode != 3) v += bias[col];
                const long long o = (long long)row * ldo + col;
                if (mode == 1) ((float*)outP)[o] = v;
                else           ((bf16*)outP)[o] = (bf16)v;
            }
        }
    }
}

// Fused value-GEMM (768 blocks) + offaw-GEMM (256 blocks) in one dispatch.
__global__ __launch_bounds__(256) void g01_kernel(
    const bf16* __restrict__ fn, const bf16* __restrict__ qn,
    const bf16* __restrict__ WvT, const bf16* __restrict__ WoffawT,
    const float* __restrict__ bv, const float* __restrict__ oabias,
    bf16* __restrict__ value, float* __restrict__ offaw)
{
    __shared__ __align__(16) bf16 As[3 * 4096];
    __shared__ __align__(16) bf16 Bs[3 * 4096];
    const int id = blockIdx.x;
    if (id < 768) {                       // value[m] = fn[m] @ WvT[m] + bv[m]
        const int rowb = id & 63, q = id >> 6;   // q 0..11
        const int colb = q % 3, m = q / 3;
        gemm_pipe(fn + (long long)m * RTOT * C_, C_,
                  WvT + (long long)m * C_ * C_, C_,
                  bv + m * C_, value + (long long)m * RTOT * C_, C_, 0,
                  rowb * 128, colb * 128, As, Bs);
    } else {                              // offaw[m] = qn @ WoffawT[m] + oabias
        const int id2 = id - 768;
        const int rowb = id2 & 63, m = id2 >> 6;
        gemm_pipe(qn, C_, WoffawT + (long long)m * 128 * C_, C_,
                  oabias + m * 128, offaw + (long long)m * RTOT * 128, 128, 1,
                  rowb * 128, 0, As, Bs);
    }
}

// out-GEMM split-K=4 (chunk = modality): partial[kc] = attn[:,kc*384:] @ Wout_kc
// Join happens in a separate dispatch (cross-XCD coherence for free at the
// kernel boundary — fused same-kernel join cost 15x in L2 writebacks, r8).
__global__ __launch_bounds__(256) void g2_kernel(
    const bf16* __restrict__ attn, const bf16* __restrict__ WoutT,
    bf16* __restrict__ partial)
{
    __shared__ __align__(16) bf16 As[3 * 4096];
    __shared__ __align__(16) bf16 Bs[3 * 4096];
    const int rowb = blockIdx.x & 63;
    const int q = blockIdx.x >> 6;        // 0..11
    const int colb = q % 3, kc = q / 3;
    gemm_pipe(attn + kc * C_, KOUT, WoutT + kc * C_, KOUT, nullptr,
              partial + (long long)kc * RTOT * C_, C_, 3,
              rowb * 128, colb * 128, As, Bs);
}

// out = query + boutbig + sum of 4 bf16 partials (deterministic split-K join)
__global__ __launch_bounds__(256) void combine_kernel(
    const bf16* __restrict__ partial, const float* __restrict__ query,
    const float* __restrict__ boutbig, float* __restrict__ out)
{
    const int i8 = (blockIdx.x * 256 + threadIdx.x) * 8;   // grid 1536 exact
    const int c0 = i8 % C_;
    float s[8];
#pragma unroll
    for (int j = 0; j < 8; ++j) s[j] = query[i8 + j] + boutbig[c0 + j];
#pragma unroll
    for (int z = 0; z < 4; ++z) {
        bf16x8 p = *reinterpret_cast<const bf16x8*>(partial + (long long)z * RTOT * C_ + i8);
#pragma unroll
        for (int j = 0; j < 8; ++j) s[j] += (float)p[j];
    }
#pragma unroll
    for (int j = 0; j < 8; ++j) out[i8 + j] = s[j];
}

// ---------------------------------------------------------------------------
// Deformable sampling. Block = 4 rows of one (m,b); 384 threads.
// Phase 1 (96 threads): per (row,h,p) softmax + bilinear -> 4 {weight,
//   byte-offset} pairs in LDS (validity folded, offsets premultiplied).
// Phase 2 (4 rows x 6 heads x 16 lanes): lane owns 4 channels, 16 u64 gathers
//   issued back-to-back (MLP), then 64 FMAs.
// Grid: bid&7 = m*2+b -> each XCD keeps one 3.1MB value slice L2-resident.
// ---------------------------------------------------------------------------
struct WP { float w; int off; };

__global__ __launch_bounds__(384) void sample_kernel(
    const float* __restrict__ offaw, const float* __restrict__ ref,
    const bf16* __restrict__ value, bf16* __restrict__ attn)
{
    const int bid   = blockIdx.x;
    const int combo = bid & 7;
    const int quad  = bid >> 3;          // 0..1023
    const int m = combo >> 1, b = combo & 1;
    const int r0 = b * 4096 + quad * 4;

    __shared__ WP wp_s[4][24][4];

    const int t = threadIdx.x;
    if (t < 96) {
        const int row = t / 24;
        const int i   = t % 24;          // h*4+p  (aligned-4 groups: same row,h)
        const int h = i >> 2, p = i & 3;
        const int r = r0 + row;
        const float* oa = offaw + ((long long)m * RTOT + r) * 128;
        float e = oa[48 + h * 4 + p];
        float mx = fmaxf(e, __shfl_xor(e, 1));
        mx = fmaxf(mx, __shfl_xor(mx, 2));
        float ex = expf(e - mx);
        float s = ex;
        s += __shfl_xor(s, 1);
        s += __shfl_xor(s, 2);
        const float aw = ex / s;
        const float x = ref[r * 2 + 0] * 64.f - 0.5f + oa[h * 8 + p * 2 + 0];
        const float y = ref[r * 2 + 1] * 64.f - 0.5f + oa[h * 8 + p * 2 + 1];
        const float xf = floorf(x), yf = floorf(y);
        const float wx = x - xf, wy = y - yf;
        const int x0 = (int)xf, y0 = (int)yf;
        const bool xok0 = (x0 >= 0) && (x0 < 64);
        const bool xok1 = (x0 >= -1) && (x0 < 63);
        const bool yok0 = (y0 >= 0) && (y0 < 64);
        const bool yok1 = (y0 >= -1) && (y0 < 63);
        const int xc0 = min(max(x0, 0), 63),     xc1 = min(max(x0 + 1, 0), 63);
        const int yc0 = min(max(y0, 0), 63),     yc1 = min(max(y0 + 1, 0), 63);
        WP w0 = { aw * (1.f - wx) * (1.f - wy) * (float)(xok0 && yok0), (yc0 * 64 + xc0) * (C_ * 2) };
        WP w1 = { aw * wx         * (1.f - wy) * (float)(xok1 && yok0), (yc0 * 64 + xc1) * (C_ * 2) };
        WP w2 = { aw * (1.f - wx) * wy         * (float)(xok0 && yok1), (yc1 * 64 + xc0) * (C_ * 2) };
        WP w3 = { aw * wx         * wy         * (float)(xok1 && yok1), (yc1 * 64 + xc1) * (C_ * 2) };
        wp_s[row][i][0] = w0;  wp_s[row][i][1] = w1;
        wp_s[row][i][2] = w2;  wp_s[row][i][3] = w3;
    }
    __syncthreads();

    const int row = t / 96;              // 0..3
    const int tl  = t % 96;
    const int h   = tl >> 4;             // 0..5
    const int l16 = tl & 15;             // 4 channels each
    const int r   = r0 + row;
    const char* vb = (const char*)(value
        + ((long long)m * RTOT + (long long)b * 4096) * C_ + h * 64 + l16 * 4);

    float wreg[16]; int oreg[16]; unsigned long long vreg[16];
#pragma unroll
    for (int i = 0; i < 16; ++i) {
        WP wp = wp_s[row][h * 4 + (i >> 2)][i & 3];
        wreg[i] = wp.w; oreg[i] = wp.off;
    }
#pragma unroll
    for (int i = 0; i < 16; ++i)
        vreg[i] = *reinterpret_cast<const unsigned long long*>(vb + oreg[i]);
    float a0 = 0.f, a1 = 0.f, a2 = 0.f, a3 = 0.f;
#pragma unroll
    for (int i = 0; i < 16; ++i) {
        const unsigned int lo = (unsigned int)vreg[i];
        const unsigned int hi = (unsigned int)(vreg[i] >> 32);
        a0 += wreg[i] * __builtin_bit_cast(float, lo << 16);
        a1 += wreg[i] * __builtin_bit_cast(float, lo & 0xffff0000u);
        a2 += wreg[i] * __builtin_bit_cast(float, hi << 16);
        a3 += wreg[i] * __builtin_bit_cast(float, hi & 0xffff0000u);
    }
    union { bf16 h4[4]; unsigned long long u; } o;
    o.h4[0] = (bf16)a0; o.h4[1] = (bf16)a1; o.h4[2] = (bf16)a2; o.h4[3] = (bf16)a3;
    *reinterpret_cast<unsigned long long*>(attn + (long long)r * KOUT + m * C_ + h * 64 + l16 * 4) = o.u;
}

// ---------------------------------------------------------------------------
extern "C" void kernel_launch(void* const* d_in, const int* in_sizes, int n_in,
                              void* d_out, int out_size, void* d_ws, size_t ws_size,
                              hipStream_t stream)
{
    const float* query      = (const float*)d_in[0];
    const float* ref        = (const float*)d_in[1];
    const float* feat       = (const float*)d_in[2];
    const float* feat_other = (const float*)d_in[3];
    const float* qn_g = (const float*)d_in[4];
    const float* qn_b = (const float*)d_in[5];
    const float* fn_g = (const float*)d_in[6];
    const float* fn_b = (const float*)d_in[7];
    const float* Wv   = (const float*)d_in[8];
    const float* bv   = (const float*)d_in[9];
    const float* Woff = (const float*)d_in[10];
    const float* boff = (const float*)d_in[11];
    const float* Waw  = (const float*)d_in[12];
    const float* baw  = (const float*)d_in[13];
    const float* Wout = (const float*)d_in[14];
    const float* bout = (const float*)d_in[15];
    const float* gamma = (const float*)d_in[16];
    float* out = (float*)d_out;

    char* ws = (char*)d_ws;
    size_t off = 0;
    auto carve = [&](size_t bytes) { char* p = ws + off; off += (bytes + 255) & ~(size_t)255; return p; };
    bf16*  qn      = (bf16*)carve((size_t)RTOT * C_ * 2);
    bf16*  fn      = (bf16*)carve((size_t)M_ * RTOT * C_ * 2);
    bf16*  value   = (bf16*)carve((size_t)M_ * RTOT * C_ * 2);
    bf16*  attn    = (bf16*)carve((size_t)RTOT * KOUT * 2);
    bf16*  partial = (bf16*)carve((size_t)M_ * RTOT * C_ * 2);
    float* offaw   = (float*)carve((size_t)M_ * RTOT * 128 * 4);
    bf16*  WvT     = (bf16*)carve((size_t)M_ * C_ * C_ * 2);
    bf16*  WoffawT = (bf16*)carve((size_t)M_ * 128 * C_ * 2);
    bf16*  WoutT   = (bf16*)carve((size_t)C_ * KOUT * 2);
    float* oabias  = (float*)carve((size_t)M_ * 128 * 4);
    float* boutbig = (float*)carve((size_t)C_ * 4);

    // prep: LN (10240 blocks) + weight cvt (1024 blocks)
    prep_kernel<<<11264, 256, 0, stream>>>(query, feat, feat_other,
                                           qn_g, qn_b, fn_g, fn_b, qn, fn,
                                           Wv, Woff, Waw, Wout, gamma, boff, baw, bout,
                                           WvT, WoffawT, WoutT, oabias, boutbig);
    // value[m] (768 blocks) + offaw[m] (256 blocks), one dispatch
    g01_kernel<<<1024, 256, 0, stream>>>(fn, qn, WvT, WoffawT, bv, oabias, value, offaw);
    // sampling -> attn [R][1536] bf16
    sample_kernel<<<dim3(RTOT * M_ / 4), 384, 0, stream>>>(offaw, ref, value, attn);
    // split-K out-GEMM: partial[kc] = attn_kc @ WoutT_kc  (768 blocks)
    g2_kernel<<<768, 256, 0, stream>>>(attn, WoutT, partial);
    // out = query + boutbig + sum partials
    combine_kernel<<<1536, 256, 0, stream>>>(partial, query, boutbig, out);
}

// Round 10
// 104.190 us; speedup vs baseline: 2.7718x; 1.0298x over previous
//
#include <hip/hip_runtime.h>
#include <hip/hip_bf16.h>

// Problem constants: B=2, Lq=4096, C=384, M=4, H=6, P=4, Lv=1, 64x64, Dh=64.
#define RTOT 8192      // B*Lq
#define C_   384
#define M_   4
#define KOUT 1536      // M_*C_

typedef __bf16 bf16;
typedef bf16  bf16x8 __attribute__((ext_vector_type(8)));
typedef float f32x4  __attribute__((ext_vector_type(4)));

// async global->LDS, 16B per lane, linear LDS dest (wave-uniform base + lane*16)
#define GLOAD_LDS16(g, l) __builtin_amdgcn_global_load_lds( \
    (const __attribute__((address_space(1))) unsigned int*)(g), \
    (__attribute__((address_space(3))) unsigned int*)(l), 16, 0, 0)

// counted vmcnt wait + workgroup barrier (T3/T4: never drain to 0 mid-loop).
#define WAITB(N) do { \
    asm volatile("s_waitcnt vmcnt(" #N ")\n\ts_barrier" ::: "memory"); \
    __builtin_amdgcn_sched_barrier(0); } while (0)

// ---------------------------------------------------------------------------
// prep: fused weight-prep (cvt) + LayerNorm.
//   blocks [0, 10240): LN, which = bid/2048 (0=query, 1..4=feats), 4 rows/blk
//   blocks [10240, 11264): grid-stride cvt over S4 elems
// ---------------------------------------------------------------------------
#define S0 589824    // WvT:    4*384*384
#define S1 786432    // +WoffawT: 4*128*384
#define S2 1376256   // +WoutT: 384*1536
#define S3 1376768   // +oabias: 4*128
#define S4 1377152   // +boutbig: 384

__global__ __launch_bounds__(256) void prep_kernel(
    const float* __restrict__ query, const float* __restrict__ feat,
    const float* __restrict__ feat_other,
    const float* __restrict__ qn_g, const float* __restrict__ qn_b,
    const float* __restrict__ fn_g, const float* __restrict__ fn_b,
    bf16* __restrict__ qn, bf16* __restrict__ fn,
    const float* __restrict__ Wv, const float* __restrict__ Woff,
    const float* __restrict__ Waw, const float* __restrict__ Wout,
    const float* __restrict__ gamma, const float* __restrict__ boff,
    const float* __restrict__ baw, const float* __restrict__ bout,
    bf16* __restrict__ WvT, bf16* __restrict__ WoffawT, bf16* __restrict__ WoutT,
    float* __restrict__ oabias, float* __restrict__ boutbig)
{
    const int bid = blockIdx.x;
    const int tid = threadIdx.x;
    if (bid < 10240) {
        // ---- LayerNorm: 4 waves, one row each; float2 loads, bf16x2 stores
        const int which = bid / 2048;
        const int xb    = bid % 2048;
        const int r = xb * 4 + (tid >> 6);
        const int lane = tid & 63;
        const float* src; const float* g; const float* bb; bf16* dst;
        if (which == 0) { src = query; g = qn_g; bb = qn_b; dst = qn; }
        else {
            int m = which - 1;
            src = (m == 0) ? feat : feat_other + (size_t)(m - 1) * RTOT * C_;
            g = fn_g + m * C_; bb = fn_b + m * C_; dst = fn + (size_t)m * RTOT * C_;
        }
        src += (size_t)r * C_; dst += (size_t)r * C_;
        float2 v[3]; float s = 0.f, sq = 0.f;
#pragma unroll
        for (int j = 0; j < 3; ++j) {
            v[j] = *reinterpret_cast<const float2*>(src + (lane + j * 64) * 2);
            s += v[j].x + v[j].y; sq += v[j].x * v[j].x + v[j].y * v[j].y;
        }
#pragma unroll
        for (int o = 1; o < 64; o <<= 1) {
            s += __shfl_xor(s, o);
            sq += __shfl_xor(sq, o);
        }
        const float mean = s * (1.f / C_);
        const float var  = sq * (1.f / C_) - mean * mean;
        const float rs   = rsqrtf(var + 1e-6f);
#pragma unroll
        for (int j = 0; j < 3; ++j) {
            const int c = (lane + j * 64) * 2;
            union { bf16 h2[2]; unsigned int u; } o;
            o.h2[0] = (bf16)((v[j].x - mean) * rs * g[c] + bb[c]);
            o.h2[1] = (bf16)((v[j].y - mean) * rs * g[c + 1] + bb[c + 1]);
            *reinterpret_cast<unsigned int*>(dst + c) = o.u;
        }
        return;
    }
    // ---- cvt (weight prep), grid-stride
    for (int idx = (bid - 10240) * 256 + tid; idx < S4; idx += 1024 * 256) {
        if (idx < S0) {
            int t = idx; int m = t / (C_ * C_); int rr = t % (C_ * C_);
            int n = rr / C_, k = rr % C_;
            WvT[t] = (bf16)Wv[(size_t)m * C_ * C_ + (size_t)k * C_ + n];
        } else if (idx < S1) {
            int t = idx - S0; int m = t / (128 * C_); int rr = t % (128 * C_);
            int n = rr / C_, k = rr % C_;
            float v = 0.f;
            if (n < 48)      v = Woff[(size_t)m * C_ * 48 + (size_t)k * 48 + n];
            else if (n < 72) v = Waw[(size_t)m * C_ * 24 + (size_t)k * 24 + (n - 48)];
            WoffawT[t] = (bf16)v;
        } else if (idx < S2) {
            int t = idx - S1; int n = t / KOUT; int kk = t % KOUT;
            int m = kk / C_, k = kk % C_;
            WoutT[t] = (bf16)(Wout[(size_t)m * C_ * C_ + (size_t)k * C_ + n] * gamma[m * C_ + n]);
        } else if (idx < S3) {
            int t = idx - S2; int m = t / 128; int n = t % 128;
            float v = 0.f;
            if (n < 48)      v = boff[m * 48 + n];
            else if (n < 72) v = baw[m * 24 + (n - 48)];
            oabias[t] = v;
        } else {
            int c = idx - S3;
            float s = 0.f;
            for (int m = 0; m < M_; ++m) s += gamma[m * C_ + c] * bout[m * C_ + c];
            boutbig[c] = s;
        }
    }
}

// ---------------------------------------------------------------------------
// Shared GEMM pipeline for g01: 128x128 tile, BK=32, NK=12 (K=384), 4 waves
// (2x2), 4x4 frags/wave. 3 LDS buffer pairs, 2-ahead counted vmcnt pipeline.
// Both-sides swizzle: 16B slot s of each 64B LDS row holds global col-chunk
// s ^ ((row>>1)&3); ds_read applies the same XOR.
// mode: 0 = bf16 out + bias, 1 = f32 out + bias.
// ---------------------------------------------------------------------------
__device__ __forceinline__ void gemm_pipe(
    const bf16* __restrict__ A, int lda,
    const bf16* __restrict__ W, int ldw,
    const float* __restrict__ bias,
    void* __restrict__ outP, int ldo, int mode,
    int brow, int bcol, bf16* As, bf16* Bs)
{
    const int tid = threadIdx.x;
    const int lane = tid & 63, wave = tid >> 6;
    const int wr = wave >> 1, wc = wave & 1;
    const int lr = lane & 15, lg = lane >> 4;

    const int r0 = tid >> 2, s0 = tid & 3;
    const int r1 = r0 + 64;
    const long long aoff0 = (long long)(brow + r0) * lda + (s0 ^ ((r0 >> 1) & 3)) * 8;
    const long long aoff1 = (long long)(brow + r1) * lda + (s0 ^ ((r1 >> 1) & 3)) * 8;
    const long long woff0 = (long long)(bcol + r0) * ldw + (s0 ^ ((r0 >> 1) & 3)) * 8;
    const long long woff1 = (long long)(bcol + r1) * ldw + (s0 ^ ((r1 >> 1) & 3)) * 8;

    int aRd[4], bRd[4];
#pragma unroll
    for (int i = 0; i < 4; ++i) {
        const int ra = wr * 64 + i * 16 + lr;
        const int rb = wc * 64 + i * 16 + lr;
        aRd[i] = ra * 32 + (lg ^ ((ra >> 1) & 3)) * 8;
        bRd[i] = rb * 32 + (lg ^ ((rb >> 1) & 3)) * 8;
    }

    f32x4 acc[4][4] = {};

#pragma unroll
    for (int t = 0; t < 2; ++t) {
        GLOAD_LDS16(A + aoff0 + t * 32, (char*)As + t * 8192 + tid * 16);
        GLOAD_LDS16(A + aoff1 + t * 32, (char*)As + t * 8192 + (tid + 256) * 16);
        GLOAD_LDS16(W + woff0 + t * 32, (char*)Bs + t * 8192 + tid * 16);
        GLOAD_LDS16(W + woff1 + t * 32, (char*)Bs + t * 8192 + (tid + 256) * 16);
    }

#pragma unroll
    for (int kt = 0; kt < 12; ++kt) {
        if (kt + 1 < 12) { WAITB(4); } else { WAITB(0); }
        const int cb = kt % 3, ib = (kt + 2) % 3;
        if (kt + 2 < 12) {
            GLOAD_LDS16(A + aoff0 + (kt + 2) * 32, (char*)As + ib * 8192 + tid * 16);
            GLOAD_LDS16(A + aoff1 + (kt + 2) * 32, (char*)As + ib * 8192 + (tid + 256) * 16);
            GLOAD_LDS16(W + woff0 + (kt + 2) * 32, (char*)Bs + ib * 8192 + tid * 16);
            GLOAD_LDS16(W + woff1 + (kt + 2) * 32, (char*)Bs + ib * 8192 + (tid + 256) * 16);
        }
        bf16x8 af[4], bfr[4];
#pragma unroll
        for (int mi = 0; mi < 4; ++mi)
            af[mi] = *reinterpret_cast<const bf16x8*>(&As[cb * 4096 + aRd[mi]]);
#pragma unroll
        for (int ni = 0; ni < 4; ++ni)
            bfr[ni] = *reinterpret_cast<const bf16x8*>(&Bs[cb * 4096 + bRd[ni]]);
#pragma unroll
        for (int mi = 0; mi < 4; ++mi)
#pragma unroll
            for (int ni = 0; ni < 4; ++ni)
                acc[mi][ni] = __builtin_amdgcn_mfma_f32_16x16x32_bf16(
                    af[mi], bfr[ni], acc[mi][ni], 0, 0, 0);
    }

#pragma unroll
    for (int mi = 0; mi < 4; ++mi) {
#pragma unroll
        for (int ni = 0; ni < 4; ++ni) {
#pragma unroll
            for (int rr = 0; rr < 4; ++rr) {
                const int row = brow + wr * 64 + mi * 16 + lg * 4 + rr;
                const int col = bcol + wc * 64 + ni * 16 + lr;
                float v = acc[mi][ni][rr] + bias[col];
                const long long o = (long long)row * ldo + col;
                if (mode == 1) ((float*)outP)[o] = v;
                else           ((bf16*)outP)[o] = (bf16)v;
            }
        }
    }
}

// Fused value-GEMM (768 blocks) + offaw-GEMM (256 blocks) in one dispatch.
__global__ __launch_bounds__(256) void g01_kernel(
    const bf16* __restrict__ fn, const bf16* __restrict__ qn,
    const bf16* __restrict__ WvT, const bf16* __restrict__ WoffawT,
    const float* __restrict__ bv, const float* __restrict__ oabias,
    bf16* __restrict__ value, float* __restrict__ offaw)
{
    __shared__ __align__(16) bf16 As[3 * 4096];
    __shared__ __align__(16) bf16 Bs[3 * 4096];
    const int id = blockIdx.x;
    if (id < 768) {                       // value[m] = fn[m] @ WvT[m] + bv[m]
        const int rowb = id & 63, q = id >> 6;   // q 0..11
        const int colb = q % 3, m = q / 3;
        gemm_pipe(fn + (long long)m * RTOT * C_, C_,
                  WvT + (long long)m * C_ * C_, C_,
                  bv + m * C_, value + (long long)m * RTOT * C_, C_, 0,
                  rowb * 128, colb * 128, As, Bs);
    } else {                              // offaw[m] = qn @ WoffawT[m] + oabias
        const int id2 = id - 768;
        const int rowb = id2 & 63, m = id2 >> 6;
        gemm_pipe(qn, C_, WoffawT + (long long)m * 128 * C_, C_,
                  oabias + m * 128, offaw + (long long)m * RTOT * 128, 128, 1,
                  rowb * 128, 0, As, Bs);
    }
}

// ---------------------------------------------------------------------------
// out-GEMM, full K=1536 in one block (no split-K, no combine): 128x128 tile,
// 48 K-steps, grid 192 (1 block/CU). Latency hidden by DEPTH, not TLP:
// 8 LDS buffer pairs (128 KB), 6-tiles-ahead, steady s_waitcnt vmcnt(24),
// tail 24/20/16/12/8/4/0 (compile-time literals, loop fully unrolled).
// Epilogue fuses out = acc + boutbig + query (f32).
// Same both-sides swizzle as gemm_pipe.
// ---------------------------------------------------------------------------
__global__ __launch_bounds__(256) void g2_kernel(
    const bf16* __restrict__ attn, const bf16* __restrict__ WoutT,
    const float* __restrict__ query, const float* __restrict__ boutbig,
    float* __restrict__ out)
{
    __shared__ __align__(16) bf16 As[8 * 4096];
    __shared__ __align__(16) bf16 Bs[8 * 4096];
    const int brow = (blockIdx.x & 63) * 128;
    const int bcol = (blockIdx.x >> 6) * 128;    // 0..2
    const int tid = threadIdx.x;
    const int lane = tid & 63, wave = tid >> 6;
    const int wr = wave >> 1, wc = wave & 1;
    const int lr = lane & 15, lg = lane >> 4;

    const int r0 = tid >> 2, s0 = tid & 3;
    const int r1 = r0 + 64;
    const long long aoff0 = (long long)(brow + r0) * KOUT + (s0 ^ ((r0 >> 1) & 3)) * 8;
    const long long aoff1 = (long long)(brow + r1) * KOUT + (s0 ^ ((r1 >> 1) & 3)) * 8;
    const long long woff0 = (long long)(bcol + r0) * KOUT + (s0 ^ ((r0 >> 1) & 3)) * 8;
    const long long woff1 = (long long)(bcol + r1) * KOUT + (s0 ^ ((r1 >> 1) & 3)) * 8;

    int aRd[4], bRd[4];
#pragma unroll
    for (int i = 0; i < 4; ++i) {
        const int ra = wr * 64 + i * 16 + lr;
        const int rb = wc * 64 + i * 16 + lr;
        aRd[i] = ra * 32 + (lg ^ ((ra >> 1) & 3)) * 8;
        bRd[i] = rb * 32 + (lg ^ ((rb >> 1) & 3)) * 8;
    }

    // prologue: stage tiles 0..6 (7 tiles x 4 vmem instrs/wave)
#pragma unroll
    for (int t = 0; t < 7; ++t) {
        GLOAD_LDS16(attn + aoff0 + t * 32, (char*)As + t * 8192 + tid * 16);
        GLOAD_LDS16(attn + aoff1 + t * 32, (char*)As + t * 8192 + (tid + 256) * 16);
        GLOAD_LDS16(WoutT + woff0 + t * 32, (char*)Bs + t * 8192 + tid * 16);
        GLOAD_LDS16(WoutT + woff1 + t * 32, (char*)Bs + t * 8192 + (tid + 256) * 16);
    }

    f32x4 acc[4][4] = {};
#pragma unroll
    for (int kt = 0; kt < 48; ++kt) {
        // wait for tile kt (6 tiles = 24 instrs stay in flight mid-loop)
        if (kt <= 41)      { WAITB(24); }
        else if (kt == 42) { WAITB(20); }
        else if (kt == 43) { WAITB(16); }
        else if (kt == 44) { WAITB(12); }
        else if (kt == 45) { WAITB(8);  }
        else if (kt == 46) { WAITB(4);  }
        else               { WAITB(0);  }
        if (kt + 7 < 48) {   // stage tile kt+7 into the buffer freed at kt-1
            const int ib = (kt + 7) & 7;
            GLOAD_LDS16(attn + aoff0 + (kt + 7) * 32, (char*)As + ib * 8192 + tid * 16);
            GLOAD_LDS16(attn + aoff1 + (kt + 7) * 32, (char*)As + ib * 8192 + (tid + 256) * 16);
            GLOAD_LDS16(WoutT + woff0 + (kt + 7) * 32, (char*)Bs + ib * 8192 + tid * 16);
            GLOAD_LDS16(WoutT + woff1 + (kt + 7) * 32, (char*)Bs + ib * 8192 + (tid + 256) * 16);
        }
        const int cb = kt & 7;
        bf16x8 af[4], bfr[4];
#pragma unroll
        for (int mi = 0; mi < 4; ++mi)
            af[mi] = *reinterpret_cast<const bf16x8*>(&As[cb * 4096 + aRd[mi]]);
#pragma unroll
        for (int ni = 0; ni < 4; ++ni)
            bfr[ni] = *reinterpret_cast<const bf16x8*>(&Bs[cb * 4096 + bRd[ni]]);
#pragma unroll
        for (int mi = 0; mi < 4; ++mi)
#pragma unroll
            for (int ni = 0; ni < 4; ++ni)
                acc[mi][ni] = __builtin_amdgcn_mfma_f32_16x16x32_bf16(
                    af[mi], bfr[ni], acc[mi][ni], 0, 0, 0);
    }

#pragma unroll
    for (int mi = 0; mi < 4; ++mi) {
#pragma unroll
        for (int ni = 0; ni < 4; ++ni) {
#pragma unroll
            for (int rr = 0; rr < 4; ++rr) {
                const int row = brow + wr * 64 + mi * 16 + lg * 4 + rr;
                const int col = bcol + wc * 64 + ni * 16 + lr;
                const long long o = (long long)row * C_ + col;
                out[o] = acc[mi][ni][rr] + boutbig[col] + query[o];
            }
        }
    }
}

// ---------------------------------------------------------------------------
// Deformable sampling. Block = 4 rows of one (m,b); 384 threads.
// Phase 1 (96 threads): per (row,h,p) softmax + bilinear -> 4 {weight,
//   byte-offset} pairs in LDS (validity folded, offsets premultiplied).
// Phase 2 (4 rows x 6 heads x 16 lanes): lane owns 4 channels, 16 u64 gathers
//   issued back-to-back (MLP), then 64 FMAs.
// Grid: bid&7 = m*2+b -> each XCD keeps one 3.1MB value slice L2-resident.
// ---------------------------------------------------------------------------
struct WP { float w; int off; };

__global__ __launch_bounds__(384) void sample_kernel(
    const float* __restrict__ offaw, const float* __restrict__ ref,
    const bf16* __restrict__ value, bf16* __restrict__ attn)
{
    const int bid   = blockIdx.x;
    const int combo = bid & 7;
    const int quad  = bid >> 3;          // 0..1023
    const int m = combo >> 1, b = combo & 1;
    const int r0 = b * 4096 + quad * 4;

    __shared__ WP wp_s[4][24][4];

    const int t = threadIdx.x;
    if (t < 96) {
        const int row = t / 24;
        const int i   = t % 24;          // h*4+p  (aligned-4 groups: same row,h)
        const int h = i >> 2, p = i & 3;
        const int r = r0 + row;
        const float* oa = offaw + ((long long)m * RTOT + r) * 128;
        float e = oa[48 + h * 4 + p];
        float mx = fmaxf(e, __shfl_xor(e, 1));
        mx = fmaxf(mx, __shfl_xor(mx, 2));
        float ex = expf(e - mx);
        float s = ex;
        s += __shfl_xor(s, 1);
        s += __shfl_xor(s, 2);
        const float aw = ex / s;
        const float x = ref[r * 2 + 0] * 64.f - 0.5f + oa[h * 8 + p * 2 + 0];
        const float y = ref[r * 2 + 1] * 64.f - 0.5f + oa[h * 8 + p * 2 + 1];
        const float xf = floorf(x), yf = floorf(y);
        const float wx = x - xf, wy = y - yf;
        const int x0 = (int)xf, y0 = (int)yf;
        const bool xok0 = (x0 >= 0) && (x0 < 64);
        const bool xok1 = (x0 >= -1) && (x0 < 63);
        const bool yok0 = (y0 >= 0) && (y0 < 64);
        const bool yok1 = (y0 >= -1) && (y0 < 63);
        const int xc0 = min(max(x0, 0), 63),     xc1 = min(max(x0 + 1, 0), 63);
        const int yc0 = min(max(y0, 0), 63),     yc1 = min(max(y0 + 1, 0), 63);
        WP w0 = { aw * (1.f - wx) * (1.f - wy) * (float)(xok0 && yok0), (yc0 * 64 + xc0) * (C_ * 2) };
        WP w1 = { aw * wx         * (1.f - wy) * (float)(xok1 && yok0), (yc0 * 64 + xc1) * (C_ * 2) };
        WP w2 = { aw * (1.f - wx) * wy         * (float)(xok0 && yok1), (yc1 * 64 + xc0) * (C_ * 2) };
        WP w3 = { aw * wx         * wy         * (float)(xok1 && yok1), (yc1 * 64 + xc1) * (C_ * 2) };
        wp_s[row][i][0] = w0;  wp_s[row][i][1] = w1;
        wp_s[row][i][2] = w2;  wp_s[row][i][3] = w3;
    }
    __syncthreads();

    const int row = t / 96;              // 0..3
    const int tl  = t % 96;
    const int h   = tl >> 4;             // 0..5
    const int l16 = tl & 15;             // 4 channels each
    const int r   = r0 + row;
    const char* vb = (const char*)(value
        + ((long long)m * RTOT + (long long)b * 4096) * C_ + h * 64 + l16 * 4);

    float wreg[16]; int oreg[16]; unsigned long long vreg[16];
#pragma unroll
    for (int i = 0; i < 16; ++i) {
        WP wp = wp_s[row][h * 4 + (i >> 2)][i & 3];
        wreg[i] = wp.w; oreg[i] = wp.off;
    }
#pragma unroll
    for (int i = 0; i < 16; ++i)
        vreg[i] = *reinterpret_cast<const unsigned long long*>(vb + oreg[i]);
    float a0 = 0.f, a1 = 0.f, a2 = 0.f, a3 = 0.f;
#pragma unroll
    for (int i = 0; i < 16; ++i) {
        const unsigned int lo = (unsigned int)vreg[i];
        const unsigned int hi = (unsigned int)(vreg[i] >> 32);
        a0 += wreg[i] * __builtin_bit_cast(float, lo << 16);
        a1 += wreg[i] * __builtin_bit_cast(float, lo & 0xffff0000u);
        a2 += wreg[i] * __builtin_bit_cast(float, hi << 16);
        a3 += wreg[i] * __builtin_bit_cast(float, hi & 0xffff0000u);
    }
    union { bf16 h4[4]; unsigned long long u; } o;
    o.h4[0] = (bf16)a0; o.h4[1] = (bf16)a1; o.h4[2] = (bf16)a2; o.h4[3] = (bf16)a3;
    *reinterpret_cast<unsigned long long*>(attn + (long long)r * KOUT + m * C_ + h * 64 + l16 * 4) = o.u;
}

// ---------------------------------------------------------------------------
extern "C" void kernel_launch(void* const* d_in, const int* in_sizes, int n_in,
                              void* d_out, int out_size, void* d_ws, size_t ws_size,
                              hipStream_t stream)
{
    const float* query      = (const float*)d_in[0];
    const float* ref        = (const float*)d_in[1];
    const float* feat       = (const float*)d_in[2];
    const float* feat_other = (const float*)d_in[3];
    const float* qn_g = (const float*)d_in[4];
    const float* qn_b = (const float*)d_in[5];
    const float* fn_g = (const float*)d_in[6];
    const float* fn_b = (const float*)d_in[7];
    const float* Wv   = (const float*)d_in[8];
    const float* bv   = (const float*)d_in[9];
    const float* Woff = (const float*)d_in[10];
    const float* boff = (const float*)d_in[11];
    const float* Waw  = (const float*)d_in[12];
    const float* baw  = (const float*)d_in[13];
    const float* Wout = (const float*)d_in[14];
    const float* bout = (const float*)d_in[15];
    const float* gamma = (const float*)d_in[16];
    float* out = (float*)d_out;

    char* ws = (char*)d_ws;
    size_t off = 0;
    auto carve = [&](size_t bytes) { char* p = ws + off; off += (bytes + 255) & ~(size_t)255; return p; };
    bf16*  qn      = (bf16*)carve((size_t)RTOT * C_ * 2);
    bf16*  fn      = (bf16*)carve((size_t)M_ * RTOT * C_ * 2);
    bf16*  value   = (bf16*)carve((size_t)M_ * RTOT * C_ * 2);
    bf16*  attn    = (bf16*)carve((size_t)RTOT * KOUT * 2);
    float* offaw   = (float*)carve((size_t)M_ * RTOT * 128 * 4);
    bf16*  WvT     = (bf16*)carve((size_t)M_ * C_ * C_ * 2);
    bf16*  WoffawT = (bf16*)carve((size_t)M_ * 128 * C_ * 2);
    bf16*  WoutT   = (bf16*)carve((size_t)C_ * KOUT * 2);
    float* oabias  = (float*)carve((size_t)M_ * 128 * 4);
    float* boutbig = (float*)carve((size_t)C_ * 4);

    // prep: LN (10240 blocks) + weight cvt (1024 blocks)
    prep_kernel<<<11264, 256, 0, stream>>>(query, feat, feat_other,
                                           qn_g, qn_b, fn_g, fn_b, qn, fn,
                                           Wv, Woff, Waw, Wout, gamma, boff, baw, bout,
                                           WvT, WoffawT, WoutT, oabias, boutbig);
    // value[m] (768 blocks) + offaw[m] (256 blocks), one dispatch
    g01_kernel<<<1024, 256, 0, stream>>>(fn, qn, WvT, WoffawT, bv, oabias, value, offaw);
    // sampling -> attn [R][1536] bf16
    sample_kernel<<<dim3(RTOT * M_ / 4), 384, 0, stream>>>(offaw, ref, value, attn);
    // out-GEMM: full K=1536, deep-pipelined, fused +query+bias epilogue
    g2_kernel<<<192, 256, 0, stream>>>(attn, WoutT, query, boutbig, out);
}

// Round 11
// 102.787 us; speedup vs baseline: 2.8097x; 1.0137x over previous
//
#include <hip/hip_runtime.h>
#include <hip/hip_bf16.h>

// Problem constants: B=2, Lq=4096, C=384, M=4, H=6, P=4, Lv=1, 64x64, Dh=64.
#define RTOT 8192      // B*Lq
#define C_   384
#define M_   4
#define KOUT 1536      // M_*C_

typedef __bf16 bf16;
typedef bf16  bf16x8 __attribute__((ext_vector_type(8)));
typedef float f32x4  __attribute__((ext_vector_type(4)));

// async global->LDS, 16B per lane, linear LDS dest (wave-uniform base + lane*16)
#define GLOAD_LDS16(g, l) __builtin_amdgcn_global_load_lds( \
    (const __attribute__((address_space(1))) unsigned int*)(g), \
    (__attribute__((address_space(3))) unsigned int*)(l), 16, 0, 0)

// counted vmcnt wait + workgroup barrier (T3/T4: never drain to 0 mid-loop).
#define WAITB(N) do { \
    asm volatile("s_waitcnt vmcnt(" #N ")\n\ts_barrier" ::: "memory"); \
    __builtin_amdgcn_sched_barrier(0); } while (0)

// ---------------------------------------------------------------------------
// prep: fused LayerNorm + weight prep.
//   blocks [0, 10240): LN, which = bid/2048 (0=query, 1..4=feats), 4 rows/blk
//   blocks [10240, 10528): coalesced LDS-tile transposes of Wv->WvT and
//     Wout(*gamma)->WoutT (8 matrices x 36 64x64 tiles). Fixes the 16x
//     over-fetch of the old strided elementwise transpose.
//   blocks [10528, 10592): elementwise WoffawT concat + oabias + boutbig.
// ---------------------------------------------------------------------------
#define EW_TOTAL 197504   // 4*128*384 WoffawT + 512 oabias + 384 boutbig

__global__ __launch_bounds__(256) void prep_kernel(
    const float* __restrict__ query, const float* __restrict__ feat,
    const float* __restrict__ feat_other,
    const float* __restrict__ qn_g, const float* __restrict__ qn_b,
    const float* __restrict__ fn_g, const float* __restrict__ fn_b,
    bf16* __restrict__ qn, bf16* __restrict__ fn,
    const float* __restrict__ Wv, const float* __restrict__ Woff,
    const float* __restrict__ Waw, const float* __restrict__ Wout,
    const float* __restrict__ gamma, const float* __restrict__ boff,
    const float* __restrict__ baw, const float* __restrict__ bout,
    bf16* __restrict__ WvT, bf16* __restrict__ WoffawT, bf16* __restrict__ WoutT,
    float* __restrict__ oabias, float* __restrict__ boutbig)
{
    const int bid = blockIdx.x;
    const int tid = threadIdx.x;
    if (bid < 10240) {
        // ---- LayerNorm: 4 waves, one row each; float2 loads, bf16x2 stores
        const int which = bid / 2048;
        const int xb    = bid % 2048;
        const int r = xb * 4 + (tid >> 6);
        const int lane = tid & 63;
        const float* src; const float* g; const float* bb; bf16* dst;
        if (which == 0) { src = query; g = qn_g; bb = qn_b; dst = qn; }
        else {
            int m = which - 1;
            src = (m == 0) ? feat : feat_other + (size_t)(m - 1) * RTOT * C_;
            g = fn_g + m * C_; bb = fn_b + m * C_; dst = fn + (size_t)m * RTOT * C_;
        }
        src += (size_t)r * C_; dst += (size_t)r * C_;
        float2 v[3]; float s = 0.f, sq = 0.f;
#pragma unroll
        for (int j = 0; j < 3; ++j) {
            v[j] = *reinterpret_cast<const float2*>(src + (lane + j * 64) * 2);
            s += v[j].x + v[j].y; sq += v[j].x * v[j].x + v[j].y * v[j].y;
        }
#pragma unroll
        for (int o = 1; o < 64; o <<= 1) {
            s += __shfl_xor(s, o);
            sq += __shfl_xor(sq, o);
        }
        const float mean = s * (1.f / C_);
        const float var  = sq * (1.f / C_) - mean * mean;
        const float rs   = rsqrtf(var + 1e-6f);
#pragma unroll
        for (int j = 0; j < 3; ++j) {
            const int c = (lane + j * 64) * 2;
            union { bf16 h2[2]; unsigned int u; } o;
            o.h2[0] = (bf16)((v[j].x - mean) * rs * g[c] + bb[c]);
            o.h2[1] = (bf16)((v[j].y - mean) * rs * g[c + 1] + bb[c + 1]);
            *reinterpret_cast<unsigned int*>(dst + c) = o.u;
        }
        return;
    }
    if (bid < 10528) {
        // ---- coalesced 64x64 tile transpose: WvT[m][n][k] = Wv[m][k][n];
        //      WoutT[n][m*384+k] = Wout[m][k][n] * gamma[m][n]
        __shared__ float lt[64][65];
        const int bid2 = bid - 10240;        // 0..287
        const int mm = bid2 / 36;            // 0..7 (0-3 Wv, 4-7 Wout)
        const int tt = bid2 % 36;
        const int k0 = (tt % 6) * 64, n0 = (tt / 6) * 64;
        const int m = mm & 3;
        const bool isWout = mm >= 4;
        const float* src = (isWout ? Wout : Wv) + (size_t)m * C_ * C_;
        const int nl = tid & 63;             // n within tile (coalesced dim)
        const int rg = tid >> 6;             // 0..3
        const float gmul = isWout ? gamma[m * C_ + n0 + nl] : 1.f;
#pragma unroll
        for (int j = 0; j < 16; ++j) {
            const int k = rg * 16 + j;
            lt[nl][k] = src[(size_t)(k0 + k) * C_ + n0 + nl] * gmul;
        }
        __syncthreads();
        bf16* dstbase; int ldd;
        if (isWout) { dstbase = WoutT + m * C_; ldd = KOUT; }
        else        { dstbase = WvT + (size_t)m * C_ * C_; ldd = C_; }
        const int kp  = tid & 31;            // k-pair (u32-packed bf16x2)
        const int rg2 = tid >> 5;            // 0..7
#pragma unroll
        for (int j = 0; j < 8; ++j) {
            const int rn = rg2 * 8 + j;
            union { bf16 h2[2]; unsigned int u; } o;
            o.h2[0] = (bf16)lt[rn][kp * 2];
            o.h2[1] = (bf16)lt[rn][kp * 2 + 1];
            *reinterpret_cast<unsigned int*>(
                dstbase + (size_t)(n0 + rn) * ldd + k0 + kp * 2) = o.u;
        }
        return;
    }
    // ---- elementwise: WoffawT concat (+pad), oabias, boutbig
    for (int idx = (bid - 10528) * 256 + tid; idx < EW_TOTAL; idx += 64 * 256) {
        if (idx < 196608) {
            int t = idx; int m = t / (128 * C_); int rr = t % (128 * C_);
            int n = rr / C_, k = rr % C_;
            float v = 0.f;
            if (n < 48)      v = Woff[(size_t)m * C_ * 48 + (size_t)k * 48 + n];
            else if (n < 72) v = Waw[(size_t)m * C_ * 24 + (size_t)k * 24 + (n - 48)];
            WoffawT[t] = (bf16)v;
        } else if (idx < 197120) {
            int t = idx - 196608; int m = t / 128; int n = t % 128;
            float v = 0.f;
            if (n < 48)      v = boff[m * 48 + n];
            else if (n < 72) v = baw[m * 24 + (n - 48)];
            oabias[t] = v;
        } else {
            int c = idx - 197120;
            float s = 0.f;
            for (int m = 0; m < M_; ++m) s += gamma[m * C_ + c] * bout[m * C_ + c];
            boutbig[c] = s;
        }
    }
}

// ---------------------------------------------------------------------------
// Shared GEMM pipeline for g01: 128x128 tile, BK=32, NK=12 (K=384), 4 waves
// (2x2), 4x4 frags/wave. 3 LDS buffer pairs, 2-ahead counted vmcnt pipeline.
// Both-sides swizzle: 16B slot s of each 64B LDS row holds global col-chunk
// s ^ ((row>>1)&3); ds_read applies the same XOR.
// mode: 0 = bf16 out + bias, 1 = f32 out + bias.
// ---------------------------------------------------------------------------
__device__ __forceinline__ void gemm_pipe(
    const bf16* __restrict__ A, int lda,
    const bf16* __restrict__ W, int ldw,
    const float* __restrict__ bias,
    void* __restrict__ outP, int ldo, int mode,
    int brow, int bcol, bf16* As, bf16* Bs)
{
    const int tid = threadIdx.x;
    const int lane = tid & 63, wave = tid >> 6;
    const int wr = wave >> 1, wc = wave & 1;
    const int lr = lane & 15, lg = lane >> 4;

    const int r0 = tid >> 2, s0 = tid & 3;
    const int r1 = r0 + 64;
    const long long aoff0 = (long long)(brow + r0) * lda + (s0 ^ ((r0 >> 1) & 3)) * 8;
    const long long aoff1 = (long long)(brow + r1) * lda + (s0 ^ ((r1 >> 1) & 3)) * 8;
    const long long woff0 = (long long)(bcol + r0) * ldw + (s0 ^ ((r0 >> 1) & 3)) * 8;
    const long long woff1 = (long long)(bcol + r1) * ldw + (s0 ^ ((r1 >> 1) & 3)) * 8;

    int aRd[4], bRd[4];
#pragma unroll
    for (int i = 0; i < 4; ++i) {
        const int ra = wr * 64 + i * 16 + lr;
        const int rb = wc * 64 + i * 16 + lr;
        aRd[i] = ra * 32 + (lg ^ ((ra >> 1) & 3)) * 8;
        bRd[i] = rb * 32 + (lg ^ ((rb >> 1) & 3)) * 8;
    }

    f32x4 acc[4][4] = {};

#pragma unroll
    for (int t = 0; t < 2; ++t) {
        GLOAD_LDS16(A + aoff0 + t * 32, (char*)As + t * 8192 + tid * 16);
        GLOAD_LDS16(A + aoff1 + t * 32, (char*)As + t * 8192 + (tid + 256) * 16);
        GLOAD_LDS16(W + woff0 + t * 32, (char*)Bs + t * 8192 + tid * 16);
        GLOAD_LDS16(W + woff1 + t * 32, (char*)Bs + t * 8192 + (tid + 256) * 16);
    }

#pragma unroll
    for (int kt = 0; kt < 12; ++kt) {
        if (kt + 1 < 12) { WAITB(4); } else { WAITB(0); }
        const int cb = kt % 3, ib = (kt + 2) % 3;
        if (kt + 2 < 12) {
            GLOAD_LDS16(A + aoff0 + (kt + 2) * 32, (char*)As + ib * 8192 + tid * 16);
            GLOAD_LDS16(A + aoff1 + (kt + 2) * 32, (char*)As + ib * 8192 + (tid + 256) * 16);
            GLOAD_LDS16(W + woff0 + (kt + 2) * 32, (char*)Bs + ib * 8192 + tid * 16);
            GLOAD_LDS16(W + woff1 + (kt + 2) * 32, (char*)Bs + ib * 8192 + (tid + 256) * 16);
        }
        bf16x8 af[4], bfr[4];
#pragma unroll
        for (int mi = 0; mi < 4; ++mi)
            af[mi] = *reinterpret_cast<const bf16x8*>(&As[cb * 4096 + aRd[mi]]);
#pragma unroll
        for (int ni = 0; ni < 4; ++ni)
            bfr[ni] = *reinterpret_cast<const bf16x8*>(&Bs[cb * 4096 + bRd[ni]]);
#pragma unroll
        for (int mi = 0; mi < 4; ++mi)
#pragma unroll
            for (int ni = 0; ni < 4; ++ni)
                acc[mi][ni] = __builtin_amdgcn_mfma_f32_16x16x32_bf16(
                    af[mi], bfr[ni], acc[mi][ni], 0, 0, 0);
    }

#pragma unroll
    for (int mi = 0; mi < 4; ++mi) {
#pragma unroll
        for (int ni = 0; ni < 4; ++ni) {
#pragma unroll
            for (int rr = 0; rr < 4; ++rr) {
                const int row = brow + wr * 64 + mi * 16 + lg * 4 + rr;
                const int col = bcol + wc * 64 + ni * 16 + lr;
                float v = acc[mi][ni][rr] + bias[col];
                const long long o = (long long)row * ldo + col;
                if (mode == 1) ((float*)outP)[o] = v;
                else           ((bf16*)outP)[o] = (bf16)v;
            }
        }
    }
}

// Fused value-GEMM (768 blocks) + offaw-GEMM (256 blocks) in one dispatch.
__global__ __launch_bounds__(256) void g01_kernel(
    const bf16* __restrict__ fn, const bf16* __restrict__ qn,
    const bf16* __restrict__ WvT, const bf16* __restrict__ WoffawT,
    const float* __restrict__ bv, const float* __restrict__ oabias,
    bf16* __restrict__ value, float* __restrict__ offaw)
{
    __shared__ __align__(16) bf16 As[3 * 4096];
    __shared__ __align__(16) bf16 Bs[3 * 4096];
    const int id = blockIdx.x;
    if (id < 768) {                       // value[m] = fn[m] @ WvT[m] + bv[m]
        const int rowb = id & 63, q = id >> 6;   // q 0..11
        const int colb = q % 3, m = q / 3;
        gemm_pipe(fn + (long long)m * RTOT * C_, C_,
                  WvT + (long long)m * C_ * C_, C_,
                  bv + m * C_, value + (long long)m * RTOT * C_, C_, 0,
                  rowb * 128, colb * 128, As, Bs);
    } else {                              // offaw[m] = qn @ WoffawT[m] + oabias
        const int id2 = id - 768;
        const int rowb = id2 & 63, m = id2 >> 6;
        gemm_pipe(qn, C_, WoffawT + (long long)m * 128 * C_, C_,
                  oabias + m * 128, offaw + (long long)m * RTOT * 128, 128, 1,
                  rowb * 128, 0, As, Bs);
    }
}

// ---------------------------------------------------------------------------
// out-GEMM, full K=1536 in one block: 128x128 tile, 48 K-steps, grid 192.
// 8 LDS buffer pairs, 6-ahead counted vmcnt pipeline (steady vmcnt(24)).
// Epilogue fuses out = acc + boutbig + query (f32).
// ---------------------------------------------------------------------------
__global__ __launch_bounds__(256) void g2_kernel(
    const bf16* __restrict__ attn, const bf16* __restrict__ WoutT,
    const float* __restrict__ query, const float* __restrict__ boutbig,
    float* __restrict__ out)
{
    __shared__ __align__(16) bf16 As[8 * 4096];
    __shared__ __align__(16) bf16 Bs[8 * 4096];
    const int brow = (blockIdx.x & 63) * 128;
    const int bcol = (blockIdx.x >> 6) * 128;    // 0..2
    const int tid = threadIdx.x;
    const int lane = tid & 63, wave = tid >> 6;
    const int wr = wave >> 1, wc = wave & 1;
    const int lr = lane & 15, lg = lane >> 4;

    const int r0 = tid >> 2, s0 = tid & 3;
    const int r1 = r0 + 64;
    const long long aoff0 = (long long)(brow + r0) * KOUT + (s0 ^ ((r0 >> 1) & 3)) * 8;
    const long long aoff1 = (long long)(brow + r1) * KOUT + (s0 ^ ((r1 >> 1) & 3)) * 8;
    const long long woff0 = (long long)(bcol + r0) * KOUT + (s0 ^ ((r0 >> 1) & 3)) * 8;
    const long long woff1 = (long long)(bcol + r1) * KOUT + (s0 ^ ((r1 >> 1) & 3)) * 8;

    int aRd[4], bRd[4];
#pragma unroll
    for (int i = 0; i < 4; ++i) {
        const int ra = wr * 64 + i * 16 + lr;
        const int rb = wc * 64 + i * 16 + lr;
        aRd[i] = ra * 32 + (lg ^ ((ra >> 1) & 3)) * 8;
        bRd[i] = rb * 32 + (lg ^ ((rb >> 1) & 3)) * 8;
    }

#pragma unroll
    for (int t = 0; t < 7; ++t) {
        GLOAD_LDS16(attn + aoff0 + t * 32, (char*)As + t * 8192 + tid * 16);
        GLOAD_LDS16(attn + aoff1 + t * 32, (char*)As + t * 8192 + (tid + 256) * 16);
        GLOAD_LDS16(WoutT + woff0 + t * 32, (char*)Bs + t * 8192 + tid * 16);
        GLOAD_LDS16(WoutT + woff1 + t * 32, (char*)Bs + t * 8192 + (tid + 256) * 16);
    }

    f32x4 acc[4][4] = {};
#pragma unroll
    for (int kt = 0; kt < 48; ++kt) {
        if (kt <= 41)      { WAITB(24); }
        else if (kt == 42) { WAITB(20); }
        else if (kt == 43) { WAITB(16); }
        else if (kt == 44) { WAITB(12); }
        else if (kt == 45) { WAITB(8);  }
        else if (kt == 46) { WAITB(4);  }
        else               { WAITB(0);  }
        if (kt + 7 < 48) {
            const int ib = (kt + 7) & 7;
            GLOAD_LDS16(attn + aoff0 + (kt + 7) * 32, (char*)As + ib * 8192 + tid * 16);
            GLOAD_LDS16(attn + aoff1 + (kt + 7) * 32, (char*)As + ib * 8192 + (tid + 256) * 16);
            GLOAD_LDS16(WoutT + woff0 + (kt + 7) * 32, (char*)Bs + ib * 8192 + tid * 16);
            GLOAD_LDS16(WoutT + woff1 + (kt + 7) * 32, (char*)Bs + ib * 8192 + (tid + 256) * 16);
        }
        const int cb = kt & 7;
        bf16x8 af[4], bfr[4];
#pragma unroll
        for (int mi = 0; mi < 4; ++mi)
            af[mi] = *reinterpret_cast<const bf16x8*>(&As[cb * 4096 + aRd[mi]]);
#pragma unroll
        for (int ni = 0; ni < 4; ++ni)
            bfr[ni] = *reinterpret_cast<const bf16x8*>(&Bs[cb * 4096 + bRd[ni]]);
#pragma unroll
        for (int mi = 0; mi < 4; ++mi)
#pragma unroll
            for (int ni = 0; ni < 4; ++ni)
                acc[mi][ni] = __builtin_amdgcn_mfma_f32_16x16x32_bf16(
                    af[mi], bfr[ni], acc[mi][ni], 0, 0, 0);
    }

#pragma unroll
    for (int mi = 0; mi < 4; ++mi) {
#pragma unroll
        for (int ni = 0; ni < 4; ++ni) {
#pragma unroll
            for (int rr = 0; rr < 4; ++rr) {
                const int row = brow + wr * 64 + mi * 16 + lg * 4 + rr;
                const int col = bcol + wc * 64 + ni * 16 + lr;
                const long long o = (long long)row * C_ + col;
                out[o] = acc[mi][ni][rr] + boutbig[col] + query[o];
            }
        }
    }
}

// ---------------------------------------------------------------------------
// Deformable sampling. Block = 4 rows of one (m,b); 384 threads.
// Phase 1 (96 threads): per (row,h,p) softmax + bilinear -> 4 {weight,
//   byte-offset} pairs in LDS (validity folded, offsets premultiplied).
// Phase 2 (4 rows x 6 heads x 16 lanes): lane owns 4 channels, 16 u64 gathers
//   issued back-to-back (MLP), then 64 FMAs.
// Grid: bid&7 = m*2+b -> each XCD keeps one 3.1MB value slice L2-resident.
// ---------------------------------------------------------------------------
struct WP { float w; int off; };

__global__ __launch_bounds__(384) void sample_kernel(
    const float* __restrict__ offaw, const float* __restrict__ ref,
    const bf16* __restrict__ value, bf16* __restrict__ attn)
{
    const int bid   = blockIdx.x;
    const int combo = bid & 7;
    const int quad  = bid >> 3;          // 0..1023
    const int m = combo >> 1, b = combo & 1;
    const int r0 = b * 4096 + quad * 4;

    __shared__ WP wp_s[4][24][4];

    const int t = threadIdx.x;
    if (t < 96) {
        const int row = t / 24;
        const int i   = t % 24;          // h*4+p  (aligned-4 groups: same row,h)
        const int h = i >> 2, p = i & 3;
        const int r = r0 + row;
        const float* oa = offaw + ((long long)m * RTOT + r) * 128;
        float e = oa[48 + h * 4 + p];
        float mx = fmaxf(e, __shfl_xor(e, 1));
        mx = fmaxf(mx, __shfl_xor(mx, 2));
        float ex = expf(e - mx);
        float s = ex;
        s += __shfl_xor(s, 1);
        s += __shfl_xor(s, 2);
        const float aw = ex / s;
        const float x = ref[r * 2 + 0] * 64.f - 0.5f + oa[h * 8 + p * 2 + 0];
        const float y = ref[r * 2 + 1] * 64.f - 0.5f + oa[h * 8 + p * 2 + 1];
        const float xf = floorf(x), yf = floorf(y);
        const float wx = x - xf, wy = y - yf;
        const int x0 = (int)xf, y0 = (int)yf;
        const bool xok0 = (x0 >= 0) && (x0 < 64);
        const bool xok1 = (x0 >= -1) && (x0 < 63);
        const bool yok0 = (y0 >= 0) && (y0 < 64);
        const bool yok1 = (y0 >= -1) && (y0 < 63);
        const int xc0 = min(max(x0, 0), 63),     xc1 = min(max(x0 + 1, 0), 63);
        const int yc0 = min(max(y0, 0), 63),     yc1 = min(max(y0 + 1, 0), 63);
        WP w0 = { aw * (1.f - wx) * (1.f - wy) * (float)(xok0 && yok0), (yc0 * 64 + xc0) * (C_ * 2) };
        WP w1 = { aw * wx         * (1.f - wy) * (float)(xok1 && yok0), (yc0 * 64 + xc1) * (C_ * 2) };
        WP w2 = { aw * (1.f - wx) * wy         * (float)(xok0 && yok1), (yc1 * 64 + xc0) * (C_ * 2) };
        WP w3 = { aw * wx         * wy         * (float)(xok1 && yok1), (yc1 * 64 + xc1) * (C_ * 2) };
        wp_s[row][i][0] = w0;  wp_s[row][i][1] = w1;
        wp_s[row][i][2] = w2;  wp_s[row][i][3] = w3;
    }
    __syncthreads();

    const int row = t / 96;              // 0..3
    const int tl  = t % 96;
    const int h   = tl >> 4;             // 0..5
    const int l16 = tl & 15;             // 4 channels each
    const int r   = r0 + row;
    const char* vb = (const char*)(value
        + ((long long)m * RTOT + (long long)b * 4096) * C_ + h * 64 + l16 * 4);

    float wreg[16]; int oreg[16]; unsigned long long vreg[16];
#pragma unroll
    for (int i = 0; i < 16; ++i) {
        WP wp = wp_s[row][h * 4 + (i >> 2)][i & 3];
        wreg[i] = wp.w; oreg[i] = wp.off;
    }
#pragma unroll
    for (int i = 0; i < 16; ++i)
        vreg[i] = *reinterpret_cast<const unsigned long long*>(vb + oreg[i]);
    float a0 = 0.f, a1 = 0.f, a2 = 0.f, a3 = 0.f;
#pragma unroll
    for (int i = 0; i < 16; ++i) {
        const unsigned int lo = (unsigned int)vreg[i];
        const unsigned int hi = (unsigned int)(vreg[i] >> 32);
        a0 += wreg[i] * __builtin_bit_cast(float, lo << 16);
        a1 += wreg[i] * __builtin_bit_cast(float, lo & 0xffff0000u);
        a2 += wreg[i] * __builtin_bit_cast(float, hi << 16);
        a3 += wreg[i] * __builtin_bit_cast(float, hi & 0xffff0000u);
    }
    union { bf16 h4[4]; unsigned long long u; } o;
    o.h4[0] = (bf16)a0; o.h4[1] = (bf16)a1; o.h4[2] = (bf16)a2; o.h4[3] = (bf16)a3;
    *reinterpret_cast<unsigned long long*>(attn + (long long)r * KOUT + m * C_ + h * 64 + l16 * 4) = o.u;
}

// ---------------------------------------------------------------------------
extern "C" void kernel_launch(void* const* d_in, const int* in_sizes, int n_in,
                              void* d_out, int out_size, void* d_ws, size_t ws_size,
                              hipStream_t stream)
{
    const float* query      = (const float*)d_in[0];
    const float* ref        = (const float*)d_in[1];
    const float* feat       = (const float*)d_in[2];
    const float* feat_other = (const float*)d_in[3];
    const float* qn_g = (const float*)d_in[4];
    const float* qn_b = (const float*)d_in[5];
    const float* fn_g = (const float*)d_in[6];
    const float* fn_b = (const float*)d_in[7];
    const float* Wv   = (const float*)d_in[8];
    const float* bv   = (const float*)d_in[9];
    const float* Woff = (const float*)d_in[10];
    const float* boff = (const float*)d_in[11];
    const float* Waw  = (const float*)d_in[12];
    const float* baw  = (const float*)d_in[13];
    const float* Wout = (const float*)d_in[14];
    const float* bout = (const float*)d_in[15];
    const float* gamma = (const float*)d_in[16];
    float* out = (float*)d_out;

    char* ws = (char*)d_ws;
    size_t off = 0;
    auto carve = [&](size_t bytes) { char* p = ws + off; off += (bytes + 255) & ~(size_t)255; return p; };
    bf16*  qn      = (bf16*)carve((size_t)RTOT * C_ * 2);
    bf16*  fn      = (bf16*)carve((size_t)M_ * RTOT * C_ * 2);
    bf16*  value   = (bf16*)carve((size_t)M_ * RTOT * C_ * 2);
    bf16*  attn    = (bf16*)carve((size_t)RTOT * KOUT * 2);
    float* offaw   = (float*)carve((size_t)M_ * RTOT * 128 * 4);
    bf16*  WvT     = (bf16*)carve((size_t)M_ * C_ * C_ * 2);
    bf16*  WoffawT = (bf16*)carve((size_t)M_ * 128 * C_ * 2);
    bf16*  WoutT   = (bf16*)carve((size_t)C_ * KOUT * 2);
    float* oabias  = (float*)carve((size_t)M_ * 128 * 4);
    float* boutbig = (float*)carve((size_t)C_ * 4);

    // prep: LN (10240) + coalesced weight transposes (288) + elementwise (64)
    prep_kernel<<<10592, 256, 0, stream>>>(query, feat, feat_other,
                                           qn_g, qn_b, fn_g, fn_b, qn, fn,
                                           Wv, Woff, Waw, Wout, gamma, boff, baw, bout,
                                           WvT, WoffawT, WoutT, oabias, boutbig);
    // value[m] (768 blocks) + offaw[m] (256 blocks), one dispatch
    g01_kernel<<<1024, 256, 0, stream>>>(fn, qn, WvT, WoffawT, bv, oabias, value, offaw);
    // sampling -> attn [R][1536] bf16
    sample_kernel<<<dim3(RTOT * M_ / 4), 384, 0, stream>>>(offaw, ref, value, attn);
    // out-GEMM: full K=1536, deep-pipelined, fused +query+bias epilogue
    g2_kernel<<<192, 256, 0, stream>>>(attn, WoutT, query, boutbig, out);
}